// Round 1
// baseline (1663.396 us; speedup 1.0000x reference)
//
#include <hip/hip_runtime.h>
#include <hip/hip_bf16.h>

#define B_ 2
#define S_ 2048
#define H_ 4096
#define NH_ 32
#define HD_ 128
#define M_TOK (B_*S_)          // 4096 tokens
#define N_QKV (3*H_)           // 12288
#define SCALE_ 0.08838834764831845f

using bf16 = __hip_bfloat16;
typedef __attribute__((ext_vector_type(8))) short bf16x8;   // 8 bf16 = 4 VGPRs
typedef __attribute__((ext_vector_type(4))) float f32x4;

typedef __attribute__((address_space(1))) const void global_cvoid;
typedef __attribute__((address_space(3))) void lds_void;

__device__ __forceinline__ void async_ld16(const void* g, void* l) {
  __builtin_amdgcn_global_load_lds((global_cvoid*)g, (lds_void*)l, 16, 0, 0);
}

__device__ __forceinline__ unsigned short bf_bits(float x) {
  bf16 h = __float2bfloat16(x);
  return *reinterpret_cast<unsigned short*>(&h);
}

// ---------------- prep kernels ----------------

__global__ void cast_bf16_kernel(const float* __restrict__ in, bf16* __restrict__ out) {
  size_t i = ((size_t)blockIdx.x*256 + threadIdx.x)*4;
  float4 v = *(const float4*)(in + i);
  struct alignas(8) B4 { bf16 a,b,c,d; } t;
  t.a = __float2bfloat16(v.x); t.b = __float2bfloat16(v.y);
  t.c = __float2bfloat16(v.z); t.d = __float2bfloat16(v.w);
  *(B4*)(out + i) = t;
}

// out[c][r] = bf16(in[r][c]);  in: R x C f32
__global__ void transpose_cast_kernel(const float* __restrict__ in, bf16* __restrict__ out,
                                      int R, int C) {
  __shared__ float tile[32][33];
  int c0 = blockIdx.x*32, r0 = blockIdx.y*32;
  int tx = threadIdx.x, ty = threadIdx.y;
#pragma unroll
  for (int i = 0; i < 4; ++i)
    tile[ty + i*8][tx] = in[(size_t)(r0 + ty + i*8)*C + c0 + tx];
  __syncthreads();
#pragma unroll
  for (int i = 0; i < 4; ++i)
    out[(size_t)(c0 + ty + i*8)*R + r0 + tx] = __float2bfloat16(tile[tx][ty + i*8]);
}

// v (BH, S, HD) -> vt (BH, HD, S), bf16
__global__ void transpose_v_kernel(const bf16* __restrict__ in, bf16* __restrict__ out) {
  __shared__ bf16 tile[32][33];
  int bh = blockIdx.z;
  int d0 = blockIdx.x*32, s0 = blockIdx.y*32;
  int tx = threadIdx.x, ty = threadIdx.y;
#pragma unroll
  for (int i = 0; i < 4; ++i)
    tile[ty + i*8][tx] = in[((size_t)bh*S_ + s0 + ty + i*8)*HD_ + d0 + tx];
  __syncthreads();
#pragma unroll
  for (int i = 0; i < 4; ++i)
    out[((size_t)bh*HD_ + d0 + ty + i*8)*S_ + s0 + tx] = tile[tx][ty + i*8];
}

// NeoX RoPE in-place on q,k: layout (BH, S, HD), pair (d, d+64)
__global__ void rope_kernel(bf16* __restrict__ q, bf16* __restrict__ k,
                            const int* __restrict__ pos) {
  size_t idx = (size_t)blockIdx.x*256 + threadIdx.x;   // over B*NH*S*64
  int d = idx & 63;
  size_t r1 = idx >> 6;
  int s = (int)(r1 & (S_-1));
  int bh = (int)(r1 >> 11);
  int b = bh >> 5;
  int p = pos[b*S_ + s];
  // inv_freq = 10000^(-d/64) = 2^(-d*log2(10000)/64)
  float inv = exp2f(-0.2076205059304660f * (float)d);
  float ang = (float)p * inv;
  float sn, cs;
  __sincosf(ang, &sn, &cs);
  size_t base = ((size_t)bh*S_ + s)*HD_ + d;
  float x1 = __bfloat162float(q[base]), x2 = __bfloat162float(q[base+64]);
  q[base]    = __float2bfloat16(x1*cs - x2*sn);
  q[base+64] = __float2bfloat16(x2*cs + x1*sn);
  float y1 = __bfloat162float(k[base]), y2 = __bfloat162float(k[base+64]);
  k[base]    = __float2bfloat16(y1*cs - y2*sn);
  k[base+64] = __float2bfloat16(y2*cs + y1*sn);
}

// ---------------- GEMM: C[M,N] = A[M,K] * Bt[N,K]^T (+bias) ----------------
// m97 structure: 128x128 tile, BK=64, 4 waves (2x2 of 64x64), global_load_lds w16.
// EPI 0: bias add + scatter bf16 into q/k/v (B,NH,S,HD).  EPI 1: f32 direct.
template<int EPI>
__global__ __launch_bounds__(256)
void gemm_bt_kernel(const bf16* __restrict__ A, const bf16* __restrict__ Bt,
                    const float* __restrict__ bias, float* __restrict__ Cf,
                    bf16* __restrict__ qb, bf16* __restrict__ kb, bf16* __restrict__ vb,
                    int M, int N, int K)
{
  __shared__ unsigned short As[128*64];
  __shared__ unsigned short Bs[128*64];
  const int tid = threadIdx.x;
  const int wave = tid >> 6, lane = tid & 63;
  const int l15 = lane & 15, l4 = lane >> 4;
  const int bn = blockIdx.x, bm = blockIdx.y;
  const int m0 = bm*128, n0 = bn*128;
  const int wr = wave >> 1, wc = wave & 1;

  const bf16* ga = A  + (size_t)(m0 + wave*32 + (lane>>3))*K + (lane&7)*8;
  const bf16* gb = Bt + (size_t)(n0 + wave*32 + (lane>>3))*K + (lane&7)*8;
  unsigned short* lA = As + wave*32*64;
  unsigned short* lB = Bs + wave*32*64;

  f32x4 acc[4][4] = {};

  for (int kt = 0; kt < K; kt += 64) {
    __syncthreads();                       // previous tile's reads done
#pragma unroll
    for (int j = 0; j < 4; ++j) {
      async_ld16(ga + kt + (size_t)j*8*K, lA + j*8*64);
      async_ld16(gb + kt + (size_t)j*8*K, lB + j*8*64);
    }
    asm volatile("s_waitcnt vmcnt(0)" ::: "memory");
    __syncthreads();
#pragma unroll
    for (int kk = 0; kk < 2; ++kk) {
      bf16x8 af[4], bfr[4];
#pragma unroll
      for (int mi = 0; mi < 4; ++mi)
        af[mi] = *(const bf16x8*)(As + (size_t)(wr*64 + mi*16 + l15)*64 + kk*32 + l4*8);
#pragma unroll
      for (int ni = 0; ni < 4; ++ni)
        bfr[ni] = *(const bf16x8*)(Bs + (size_t)(wc*64 + ni*16 + l15)*64 + kk*32 + l4*8);
#pragma unroll
      for (int mi = 0; mi < 4; ++mi)
#pragma unroll
        for (int ni = 0; ni < 4; ++ni)
          acc[mi][ni] = __builtin_amdgcn_mfma_f32_16x16x32_bf16(af[mi], bfr[ni], acc[mi][ni], 0, 0, 0);
    }
  }

#pragma unroll
  for (int mi = 0; mi < 4; ++mi) {
#pragma unroll
    for (int ni = 0; ni < 4; ++ni) {
      int n = n0 + wc*64 + ni*16 + l15;
#pragma unroll
      for (int r = 0; r < 4; ++r) {
        int m = m0 + wr*64 + mi*16 + l4*4 + r;
        float v = acc[mi][ni][r];
        if (EPI == 0) {
          v += bias[n];
          int which = n >> 12;           // 0:q 1:k 2:v
          int h = (n >> 7) & 31;
          int d = n & 127;
          int b = m >> 11, s = m & (S_-1);
          bf16* dst = (which == 0) ? qb : (which == 1) ? kb : vb;
          dst[((size_t)(b*NH_ + h)*S_ + s)*HD_ + d] = __float2bfloat16(v);
        } else {
          Cf[(size_t)m*N + n] = v;
        }
      }
    }
  }
}

// ---------------- flash attention ----------------
// grid (qt=S/64, bh=B*NH); 4 waves, each owns 16 q-rows. KVBLK=64.
__global__ __launch_bounds__(256)
void flash_kernel(const bf16* __restrict__ q, const bf16* __restrict__ k,
                  const bf16* __restrict__ vt, bf16* __restrict__ o)
{
  __shared__ unsigned short Ks[64*136];    // K tile [64][128] pad->136
  __shared__ unsigned short Vts[128*72];   // V^T tile [128][64] pad->72
  __shared__ unsigned short Ps[4*16*72];   // per-wave P [16][64] pad->72
  const int tid = threadIdx.x;
  const int wave = tid >> 6, lane = tid & 63;
  const int l15 = lane & 15, l4 = lane >> 4;
  const int qt = blockIdx.x;
  const int bh = blockIdx.y;
  const int q0 = qt*64 + wave*16;

  bf16x8 qf[4];
#pragma unroll
  for (int kk = 0; kk < 4; ++kk)
    qf[kk] = *(const bf16x8*)(q + ((size_t)bh*S_ + q0 + l15)*HD_ + kk*32 + l4*8);

  f32x4 oacc[8] = {};
  float mst[4], lst[4];
#pragma unroll
  for (int r = 0; r < 4; ++r) { mst[r] = -1e30f; lst[r] = 0.f; }

  unsigned short* Pw = Ps + wave*16*72;

  for (int t = 0; t <= qt; ++t) {
    const int kv0 = t*64;
    __syncthreads();
    // stage K tile (1024 x 16B chunks)
#pragma unroll
    for (int i = 0; i < 4; ++i) {
      int c = tid + i*256;
      int row = c >> 4, cc = c & 15;
      *(int4*)(Ks + (size_t)row*136 + cc*8) =
        *(const int4*)(k + ((size_t)bh*S_ + kv0 + row)*HD_ + cc*8);
    }
    // stage V^T tile
#pragma unroll
    for (int i = 0; i < 4; ++i) {
      int c = tid + i*256;
      int row = c >> 3, cc = c & 7;
      *(int4*)(Vts + (size_t)row*72 + cc*8) =
        *(const int4*)(vt + ((size_t)bh*HD_ + row)*S_ + kv0 + cc*8);
    }
    __syncthreads();

    // S = Q K^T  (M=16 q, N=64 kv, K=128 d)
    f32x4 sacc[4] = {};
#pragma unroll
    for (int kk = 0; kk < 4; ++kk) {
#pragma unroll
      for (int ni = 0; ni < 4; ++ni) {
        bf16x8 kf = *(const bf16x8*)(Ks + (size_t)(ni*16 + l15)*136 + kk*32 + l4*8);
        sacc[ni] = __builtin_amdgcn_mfma_f32_16x16x32_bf16(qf[kk], kf, sacc[ni], 0, 0, 0);
      }
    }
    // scale + causal mask, row stats (row = l4*4+r, col = ni*16+l15)
    float sv[4][4];
    float rmax[4];
#pragma unroll
    for (int r = 0; r < 4; ++r) rmax[r] = -1e30f;
#pragma unroll
    for (int ni = 0; ni < 4; ++ni) {
      int kv = kv0 + ni*16 + l15;
#pragma unroll
      for (int r = 0; r < 4; ++r) {
        int qrow = q0 + l4*4 + r;
        float x = sacc[ni][r] * SCALE_;
        if (kv > qrow) x = -1e30f;
        sv[ni][r] = x;
        rmax[r] = fmaxf(rmax[r], x);
      }
    }
#pragma unroll
    for (int mm = 1; mm < 16; mm <<= 1)
#pragma unroll
      for (int r = 0; r < 4; ++r)
        rmax[r] = fmaxf(rmax[r], __shfl_xor(rmax[r], mm));
    float fac[4], rsum[4];
#pragma unroll
    for (int r = 0; r < 4; ++r) {
      float mn = fmaxf(mst[r], rmax[r]);
      fac[r] = __expf(mst[r] - mn);
      mst[r] = mn;
      rsum[r] = 0.f;
    }
#pragma unroll
    for (int ni = 0; ni < 4; ++ni) {
#pragma unroll
      for (int r = 0; r < 4; ++r) {
        float p = __expf(sv[ni][r] - mst[r]);
        rsum[r] += p;
        Pw[(size_t)(l4*4 + r)*72 + ni*16 + l15] = bf_bits(p);
      }
    }
#pragma unroll
    for (int mm = 1; mm < 16; mm <<= 1)
#pragma unroll
      for (int r = 0; r < 4; ++r)
        rsum[r] += __shfl_xor(rsum[r], mm);
#pragma unroll
    for (int r = 0; r < 4; ++r)
      lst[r] = lst[r]*fac[r] + rsum[r];
#pragma unroll
    for (int nd = 0; nd < 8; ++nd)
#pragma unroll
      for (int r = 0; r < 4; ++r)
        oacc[nd][r] *= fac[r];
    // O += P V  (M=16, N=128 d, K=64 kv)
    bf16x8 pa[2];
#pragma unroll
    for (int kk = 0; kk < 2; ++kk)
      pa[kk] = *(const bf16x8*)(Pw + (size_t)l15*72 + kk*32 + l4*8);
#pragma unroll
    for (int nd = 0; nd < 8; ++nd) {
#pragma unroll
      for (int kk = 0; kk < 2; ++kk) {
        bf16x8 vf = *(const bf16x8*)(Vts + (size_t)(nd*16 + l15)*72 + kk*32 + l4*8);
        oacc[nd] = __builtin_amdgcn_mfma_f32_16x16x32_bf16(pa[kk], vf, oacc[nd], 0, 0, 0);
      }
    }
  }

  // epilogue: normalize, write (B,S,NH,HD)
  int b = bh >> 5, h = bh & 31;
  float invl[4];
#pragma unroll
  for (int r = 0; r < 4; ++r) invl[r] = 1.f / lst[r];
#pragma unroll
  for (int nd = 0; nd < 8; ++nd)
#pragma unroll
    for (int r = 0; r < 4; ++r) {
      int qrow = q0 + l4*4 + r;
      o[((size_t)(b*S_ + qrow))*H_ + h*HD_ + nd*16 + l15] =
        __float2bfloat16(oacc[nd][r] * invl[r]);
    }
}

// ---------------- launch ----------------

extern "C" void kernel_launch(void* const* d_in, const int* in_sizes, int n_in,
                              void* d_out, int out_size, void* d_ws, size_t ws_size,
                              hipStream_t stream)
{
  const int*   positions = (const int*)d_in[0];
  const float* hidden    = (const float*)d_in[1];
  const float* Wqkv      = (const float*)d_in[2];
  const float* bqkv      = (const float*)d_in[3];
  const float* Wo        = (const float*)d_in[4];
  float* out = (float*)d_out;

  char* ws = (char*)d_ws;
  const size_t MB = 1024*1024;
  bf16* hs16    = (bf16*)(ws);               // 32 MB (reused as attn output later)
  bf16* wqkvT   = (bf16*)(ws + 32*MB);       // 96 MB  [12288][4096]
  bf16* woT     = (bf16*)(ws + 128*MB);      // 32 MB  [4096][4096]
  bf16* qbuf    = (bf16*)(ws + 160*MB);      // 32 MB  (B,NH,S,HD)
  bf16* kbuf    = (bf16*)(ws + 192*MB);      // 32 MB
  bf16* vbuf    = (bf16*)(ws + 224*MB);      // 32 MB
  bf16* vtbuf   = (bf16*)(ws + 256*MB);      // 32 MB  (B,NH,HD,S)
  bf16* attnbuf = hs16;                      // reuse

  cast_bf16_kernel<<<dim3((M_TOK*(size_t)H_)/1024), dim3(256), 0, stream>>>(hidden, hs16);
  transpose_cast_kernel<<<dim3(N_QKV/32, H_/32), dim3(32,8), 0, stream>>>(Wqkv, wqkvT, H_, N_QKV);
  transpose_cast_kernel<<<dim3(H_/32, H_/32), dim3(32,8), 0, stream>>>(Wo, woT, H_, H_);

  gemm_bt_kernel<0><<<dim3(N_QKV/128, M_TOK/128), dim3(256), 0, stream>>>(
      hs16, wqkvT, bqkv, nullptr, qbuf, kbuf, vbuf, M_TOK, N_QKV, H_);

  rope_kernel<<<dim3((B_*NH_*S_*64)/256), dim3(256), 0, stream>>>(qbuf, kbuf, positions);

  transpose_v_kernel<<<dim3(HD_/32, S_/32, B_*NH_), dim3(32,8), 0, stream>>>(vbuf, vtbuf);

  flash_kernel<<<dim3(S_/64, B_*NH_), dim3(256), 0, stream>>>(qbuf, kbuf, vtbuf, attnbuf);

  gemm_bt_kernel<1><<<dim3(H_/128, M_TOK/128), dim3(256), 0, stream>>>(
      attnbuf, woT, nullptr, out, nullptr, nullptr, nullptr, M_TOK, H_, H_);
}

// Round 2
// 1364.282 us; speedup vs baseline: 1.2192x; 1.2192x over previous
//
#include <hip/hip_runtime.h>
#include <hip/hip_bf16.h>

#define B_ 2
#define S_ 2048
#define H_ 4096
#define NH_ 32
#define HD_ 128
#define M_TOK (B_*S_)          // 4096 tokens
#define N_QKV (3*H_)           // 12288
#define SCALE_ 0.08838834764831845f

using bf16 = __hip_bfloat16;
typedef __attribute__((ext_vector_type(8))) short bf16x8;   // 8 bf16 = 4 VGPRs
typedef __attribute__((ext_vector_type(4))) float f32x4;

typedef __attribute__((address_space(1))) const void global_cvoid;
typedef __attribute__((address_space(3))) void lds_void;

__device__ __forceinline__ void async_ld16(const void* g, void* l) {
  __builtin_amdgcn_global_load_lds((global_cvoid*)g, (lds_void*)l, 16, 0, 0);
}

__device__ __forceinline__ unsigned short bf_bits(float x) {
  bf16 h = __float2bfloat16(x);
  return *reinterpret_cast<unsigned short*>(&h);
}

// ---------------- prep kernels ----------------

__global__ void cast_bf16_kernel(const float* __restrict__ in, bf16* __restrict__ out) {
  size_t i = ((size_t)blockIdx.x*256 + threadIdx.x)*4;
  float4 v = *(const float4*)(in + i);
  struct alignas(8) B4 { bf16 a,b,c,d; } t;
  t.a = __float2bfloat16(v.x); t.b = __float2bfloat16(v.y);
  t.c = __float2bfloat16(v.z); t.d = __float2bfloat16(v.w);
  *(B4*)(out + i) = t;
}

// out[c][r] = bf16(in[r][c]);  in: R x C f32
__global__ void transpose_cast_kernel(const float* __restrict__ in, bf16* __restrict__ out,
                                      int R, int C) {
  __shared__ float tile[32][33];
  int c0 = blockIdx.x*32, r0 = blockIdx.y*32;
  int tx = threadIdx.x, ty = threadIdx.y;
#pragma unroll
  for (int i = 0; i < 4; ++i)
    tile[ty + i*8][tx] = in[(size_t)(r0 + ty + i*8)*C + c0 + tx];
  __syncthreads();
#pragma unroll
  for (int i = 0; i < 4; ++i)
    out[(size_t)(c0 + ty + i*8)*R + r0 + tx] = __float2bfloat16(tile[tx][ty + i*8]);
}

// v (BH, S, HD) -> vt (BH, HD, S), bf16
__global__ void transpose_v_kernel(const bf16* __restrict__ in, bf16* __restrict__ out) {
  __shared__ bf16 tile[32][33];
  int bh = blockIdx.z;
  int d0 = blockIdx.x*32, s0 = blockIdx.y*32;
  int tx = threadIdx.x, ty = threadIdx.y;
#pragma unroll
  for (int i = 0; i < 4; ++i)
    tile[ty + i*8][tx] = in[((size_t)bh*S_ + s0 + ty + i*8)*HD_ + d0 + tx];
  __syncthreads();
#pragma unroll
  for (int i = 0; i < 4; ++i)
    out[((size_t)bh*HD_ + d0 + ty + i*8)*S_ + s0 + tx] = tile[tx][ty + i*8];
}

// NeoX RoPE in-place on q,k: layout (BH, S, HD), pair (d, d+64)
__global__ void rope_kernel(bf16* __restrict__ q, bf16* __restrict__ k,
                            const int* __restrict__ pos) {
  size_t idx = (size_t)blockIdx.x*256 + threadIdx.x;   // over B*NH*S*64
  int d = idx & 63;
  size_t r1 = idx >> 6;
  int s = (int)(r1 & (S_-1));
  int bh = (int)(r1 >> 11);
  int b = bh >> 5;
  int p = pos[b*S_ + s];
  float inv = exp2f(-0.2076205059304660f * (float)d);
  float ang = (float)p * inv;
  float sn, cs;
  __sincosf(ang, &sn, &cs);
  size_t base = ((size_t)bh*S_ + s)*HD_ + d;
  float x1 = __bfloat162float(q[base]), x2 = __bfloat162float(q[base+64]);
  q[base]    = __float2bfloat16(x1*cs - x2*sn);
  q[base+64] = __float2bfloat16(x2*cs + x1*sn);
  float y1 = __bfloat162float(k[base]), y2 = __bfloat162float(k[base+64]);
  k[base]    = __float2bfloat16(y1*cs - y2*sn);
  k[base+64] = __float2bfloat16(y2*cs + y1*sn);
}

// ---------------- GEMM: 256x256 8-phase (T1+T2+T3+T4+T5) ----------------
// C[M,N] = A[M,K] * Bt[N,K]^T (+bias). 512 thr = 8 waves (2M x 4N).
// LDS: per op 2 dbuf x 2 halves x [128][64] bf16 = 64 KB; total 128 KB.
// Swizzle: 16B-slot c stored at c^(row&7); pre-swizzled global source,
// linear global_load_lds dest, swizzled ds_read (rule #21 both-sides).
// EPI 0: bias add + scatter bf16 into q/k/v (B,NH,S,HD).  EPI 1: f32 direct.

#define BAR __builtin_amdgcn_s_barrier()
#define LGKM0 do{ asm volatile("s_waitcnt lgkmcnt(0)":::"memory"); __builtin_amdgcn_sched_barrier(0);}while(0)
#define VMW(N) asm volatile("s_waitcnt vmcnt(" #N ")":::"memory")

#define LOAD_AF(HALF) do{ const unsigned short* Ab=&As[db][HALF][0]; \
  _Pragma("unroll") for(int mi=0;mi<4;++mi) _Pragma("unroll") for(int kk=0;kk<2;++kk) \
    af[mi][kk] = *(const bf16x8*)(Ab + (wr*64+mi*16+l15)*64 + (((kk*4+l4)^sw)<<3)); }while(0)

#define LOAD_BF(DEST,HALF) do{ const unsigned short* Bb=&Bs[db][HALF][0]; \
  _Pragma("unroll") for(int ni=0;ni<2;++ni) _Pragma("unroll") for(int kk=0;kk<2;++kk) \
    DEST[ni][kk] = *(const bf16x8*)(Bb + (wc*32+ni*16+l15)*64 + (((kk*4+l4)^sw)<<3)); }while(0)

#define MFMA16(QM,QN,BQ) do{ __builtin_amdgcn_s_setprio(1); \
  _Pragma("unroll") for(int mi=0;mi<4;++mi) _Pragma("unroll") for(int ni=0;ni<2;++ni) \
    _Pragma("unroll") for(int kk=0;kk<2;++kk) \
      acc[QM][QN][mi][ni] = __builtin_amdgcn_mfma_f32_16x16x32_bf16(af[mi][kk], BQ[ni][kk], acc[QM][QN][mi][ni],0,0,0); \
  __builtin_amdgcn_s_setprio(0); }while(0)

template<int EPI>
__global__ __launch_bounds__(512, 2)
void gemm8_kernel(const bf16* __restrict__ A, const bf16* __restrict__ Bt,
                  const float* __restrict__ bias, float* __restrict__ Cf,
                  bf16* __restrict__ qb, bf16* __restrict__ kb, bf16* __restrict__ vb,
                  int M, int N, int K)
{
  __shared__ alignas(16) unsigned short As[2][2][128*64];
  __shared__ alignas(16) unsigned short Bs[2][2][128*64];

  const int tid = threadIdx.x;
  const int wave = tid >> 6, lane = tid & 63;
  const int l15 = lane & 15, l4 = lane >> 4;
  const int sw = l15 & 7;
  const int wr = wave >> 2, wc = wave & 3;     // 2 x 4 wave grid

  // XCD-bijective block swizzle (nwg % 8 == 0 for both our GEMMs)
  const int gn = N >> 8;
  const int nwg = gridDim.x;
  const int orig = blockIdx.x;
  const int wg = (orig & 7)*(nwg >> 3) + (orig >> 3);
  const int bm = wg / gn, bn = wg % gn;
  const int m0 = bm*256, n0 = bn*256;
  const int NT = K >> 6;

  // stage one half-tile (128 rows x 64 cols): 2 x global_load_lds(16B)/thread
  auto stA = [&](int buf, int h, int koff) {
#pragma unroll
    for (int j = 0; j < 2; ++j) {
      int ci = (j << 9) + tid;
      int row = ci >> 3;
      int sl = (ci & 7) ^ (row & 7);
      async_ld16(A + (size_t)(m0 + h*128 + row)*K + koff + sl*8, &As[buf][h][ci*8]);
    }
  };
  auto stB = [&](int buf, int h, int koff) {
#pragma unroll
    for (int j = 0; j < 2; ++j) {
      int ci = (j << 9) + tid;
      int row = ci >> 3;
      int sl = (ci & 7) ^ (row & 7);
      async_ld16(Bt + (size_t)(n0 + h*128 + row)*K + koff + sl*8, &Bs[buf][h][ci*8]);
    }
  };

  f32x4 acc[2][2][4][2] = {};
  bf16x8 af[4][2], bq0[2][2], bq1[2][2];

  // prologue: 6 half-tiles (3 ahead)
  stA(0,0,0); stB(0,0,0); stA(0,1,0); stB(0,1,0); stA(1,0,64); stB(1,0,64);
  VMW(8); BAR;

  for (int t = 0; t < NT-1; ++t) {
    const int db = t & 1;
    // ph0: quadrant (0,0); stage A1(t+1)
    LOAD_AF(0); LOAD_BF(bq0,0);
    stA(db^1, 1, (t+1)*64);
    BAR; LGKM0; MFMA16(0,0,bq0);
    VMW(6); BAR;
    // ph1: quadrant (0,1); stage B1(t+1)
    LOAD_BF(bq1,1);
    stB(db^1, 1, (t+1)*64);
    BAR; LGKM0; MFMA16(0,1,bq1);
    BAR;
    // ph2: quadrant (1,0); stage A0(t+2)
    LOAD_AF(1);
    if (t+2 < NT) stA(db, 0, (t+2)*64);
    BAR; LGKM0; MFMA16(1,0,bq0);
    BAR;
    // ph3: quadrant (1,1); stage B0(t+2)
    if (t+2 < NT) stB(db, 0, (t+2)*64);
    BAR; MFMA16(1,1,bq1);
    if (t+2 < NT) { VMW(8); } else { VMW(4); }
    BAR;
  }
  // final tile (no stages; drain)
  {
    const int db = (NT-1) & 1;
    LOAD_AF(0); LOAD_BF(bq0,0);
    BAR; LGKM0; MFMA16(0,0,bq0);
    VMW(0); BAR;
    LOAD_BF(bq1,1);
    BAR; LGKM0; MFMA16(0,1,bq1);
    BAR;
    LOAD_AF(1);
    BAR; LGKM0; MFMA16(1,0,bq0);
    BAR;
    MFMA16(1,1,bq1);
  }

  // epilogue
#pragma unroll
  for (int qm = 0; qm < 2; ++qm)
#pragma unroll
  for (int qn = 0; qn < 2; ++qn)
#pragma unroll
  for (int mi = 0; mi < 4; ++mi)
#pragma unroll
  for (int ni = 0; ni < 2; ++ni) {
    int n = n0 + qn*128 + wc*32 + ni*16 + l15;
#pragma unroll
    for (int r = 0; r < 4; ++r) {
      int m = m0 + qm*128 + wr*64 + mi*16 + l4*4 + r;
      float v = acc[qm][qn][mi][ni][r];
      if (EPI == 0) {
        v += bias[n];
        int which = n >> 12;           // 0:q 1:k 2:v
        int h = (n >> 7) & 31;
        int d = n & 127;
        int b = m >> 11, s = m & (S_-1);
        bf16* dst = (which == 0) ? qb : (which == 1) ? kb : vb;
        dst[((size_t)(b*NH_ + h)*S_ + s)*HD_ + d] = __float2bfloat16(v);
      } else {
        Cf[(size_t)m*N + n] = v;
      }
    }
  }
}

// ---------------- flash attention ----------------
// grid (qt=S/64, bh=B*NH); 4 waves, each owns 16 q-rows. KVBLK=64.
__global__ __launch_bounds__(256)
void flash_kernel(const bf16* __restrict__ q, const bf16* __restrict__ k,
                  const bf16* __restrict__ vt, bf16* __restrict__ o)
{
  __shared__ unsigned short Ks[64*136];    // K tile [64][128] pad->136
  __shared__ unsigned short Vts[128*72];   // V^T tile [128][64] pad->72
  __shared__ unsigned short Ps[4*16*72];   // per-wave P [16][64] pad->72
  const int tid = threadIdx.x;
  const int wave = tid >> 6, lane = tid & 63;
  const int l15 = lane & 15, l4 = lane >> 4;
  const int qt = blockIdx.x;
  const int bh = blockIdx.y;
  const int q0 = qt*64 + wave*16;

  bf16x8 qf[4];
#pragma unroll
  for (int kk = 0; kk < 4; ++kk)
    qf[kk] = *(const bf16x8*)(q + ((size_t)bh*S_ + q0 + l15)*HD_ + kk*32 + l4*8);

  f32x4 oacc[8] = {};
  float mst[4], lst[4];
#pragma unroll
  for (int r = 0; r < 4; ++r) { mst[r] = -1e30f; lst[r] = 0.f; }

  unsigned short* Pw = Ps + wave*16*72;

  for (int t = 0; t <= qt; ++t) {
    const int kv0 = t*64;
    __syncthreads();
#pragma unroll
    for (int i = 0; i < 4; ++i) {
      int c = tid + i*256;
      int row = c >> 4, cc = c & 15;
      *(int4*)(Ks + (size_t)row*136 + cc*8) =
        *(const int4*)(k + ((size_t)bh*S_ + kv0 + row)*HD_ + cc*8);
    }
#pragma unroll
    for (int i = 0; i < 4; ++i) {
      int c = tid + i*256;
      int row = c >> 3, cc = c & 7;
      *(int4*)(Vts + (size_t)row*72 + cc*8) =
        *(const int4*)(vt + ((size_t)bh*HD_ + row)*S_ + kv0 + cc*8);
    }
    __syncthreads();

    f32x4 sacc[4] = {};
#pragma unroll
    for (int kk = 0; kk < 4; ++kk) {
#pragma unroll
      for (int ni = 0; ni < 4; ++ni) {
        bf16x8 kf = *(const bf16x8*)(Ks + (size_t)(ni*16 + l15)*136 + kk*32 + l4*8);
        sacc[ni] = __builtin_amdgcn_mfma_f32_16x16x32_bf16(qf[kk], kf, sacc[ni], 0, 0, 0);
      }
    }
    float sv[4][4];
    float rmax[4];
#pragma unroll
    for (int r = 0; r < 4; ++r) rmax[r] = -1e30f;
#pragma unroll
    for (int ni = 0; ni < 4; ++ni) {
      int kv = kv0 + ni*16 + l15;
#pragma unroll
      for (int r = 0; r < 4; ++r) {
        int qrow = q0 + l4*4 + r;
        float x = sacc[ni][r] * SCALE_;
        if (kv > qrow) x = -1e30f;
        sv[ni][r] = x;
        rmax[r] = fmaxf(rmax[r], x);
      }
    }
#pragma unroll
    for (int mm = 1; mm < 16; mm <<= 1)
#pragma unroll
      for (int r = 0; r < 4; ++r)
        rmax[r] = fmaxf(rmax[r], __shfl_xor(rmax[r], mm));
    float fac[4], rsum[4];
#pragma unroll
    for (int r = 0; r < 4; ++r) {
      float mn = fmaxf(mst[r], rmax[r]);
      fac[r] = __expf(mst[r] - mn);
      mst[r] = mn;
      rsum[r] = 0.f;
    }
#pragma unroll
    for (int ni = 0; ni < 4; ++ni) {
#pragma unroll
      for (int r = 0; r < 4; ++r) {
        float p = __expf(sv[ni][r] - mst[r]);
        rsum[r] += p;
        Pw[(size_t)(l4*4 + r)*72 + ni*16 + l15] = bf_bits(p);
      }
    }
#pragma unroll
    for (int mm = 1; mm < 16; mm <<= 1)
#pragma unroll
      for (int r = 0; r < 4; ++r)
        rsum[r] += __shfl_xor(rsum[r], mm);
#pragma unroll
    for (int r = 0; r < 4; ++r)
      lst[r] = lst[r]*fac[r] + rsum[r];
#pragma unroll
    for (int nd = 0; nd < 8; ++nd)
#pragma unroll
      for (int r = 0; r < 4; ++r)
        oacc[nd][r] *= fac[r];
    bf16x8 pa[2];
#pragma unroll
    for (int kk = 0; kk < 2; ++kk)
      pa[kk] = *(const bf16x8*)(Pw + (size_t)l15*72 + kk*32 + l4*8);
#pragma unroll
    for (int nd = 0; nd < 8; ++nd) {
#pragma unroll
      for (int kk = 0; kk < 2; ++kk) {
        bf16x8 vf = *(const bf16x8*)(Vts + (size_t)(nd*16 + l15)*72 + kk*32 + l4*8);
        oacc[nd] = __builtin_amdgcn_mfma_f32_16x16x32_bf16(pa[kk], vf, oacc[nd], 0, 0, 0);
      }
    }
  }

  int b = bh >> 5, h = bh & 31;
  float invl[4];
#pragma unroll
  for (int r = 0; r < 4; ++r) invl[r] = 1.f / lst[r];
#pragma unroll
  for (int nd = 0; nd < 8; ++nd)
#pragma unroll
    for (int r = 0; r < 4; ++r) {
      int qrow = q0 + l4*4 + r;
      o[((size_t)(b*S_ + qrow))*H_ + h*HD_ + nd*16 + l15] =
        __float2bfloat16(oacc[nd][r] * invl[r]);
    }
}

// ---------------- launch ----------------

extern "C" void kernel_launch(void* const* d_in, const int* in_sizes, int n_in,
                              void* d_out, int out_size, void* d_ws, size_t ws_size,
                              hipStream_t stream)
{
  const int*   positions = (const int*)d_in[0];
  const float* hidden    = (const float*)d_in[1];
  const float* Wqkv      = (const float*)d_in[2];
  const float* bqkv      = (const float*)d_in[3];
  const float* Wo        = (const float*)d_in[4];
  float* out = (float*)d_out;

  char* ws = (char*)d_ws;
  const size_t MB = 1024*1024;
  bf16* hs16    = (bf16*)(ws);               // 32 MB (reused as attn output later)
  bf16* wqkvT   = (bf16*)(ws + 32*MB);       // 96 MB  [12288][4096]
  bf16* woT     = (bf16*)(ws + 128*MB);      // 32 MB  [4096][4096]
  bf16* qbuf    = (bf16*)(ws + 160*MB);      // 32 MB  (B,NH,S,HD)
  bf16* kbuf    = (bf16*)(ws + 192*MB);      // 32 MB
  bf16* vbuf    = (bf16*)(ws + 224*MB);      // 32 MB
  bf16* vtbuf   = (bf16*)(ws + 256*MB);      // 32 MB  (B,NH,HD,S)
  bf16* attnbuf = hs16;                      // reuse

  cast_bf16_kernel<<<dim3((M_TOK*(size_t)H_)/1024), dim3(256), 0, stream>>>(hidden, hs16);
  transpose_cast_kernel<<<dim3(N_QKV/32, H_/32), dim3(32,8), 0, stream>>>(Wqkv, wqkvT, H_, N_QKV);
  transpose_cast_kernel<<<dim3(H_/32, H_/32), dim3(32,8), 0, stream>>>(Wo, woT, H_, H_);

  gemm8_kernel<0><<<dim3((M_TOK/256)*(N_QKV/256)), dim3(512), 0, stream>>>(
      hs16, wqkvT, bqkv, nullptr, qbuf, kbuf, vbuf, M_TOK, N_QKV, H_);

  rope_kernel<<<dim3((B_*NH_*S_*64)/256), dim3(256), 0, stream>>>(qbuf, kbuf, positions);

  transpose_v_kernel<<<dim3(HD_/32, S_/32, B_*NH_), dim3(32,8), 0, stream>>>(vbuf, vtbuf);

  flash_kernel<<<dim3(S_/64, B_*NH_), dim3(256), 0, stream>>>(qbuf, kbuf, vtbuf, attnbuf);

  gemm8_kernel<1><<<dim3((M_TOK/256)*(H_/256)), dim3(512), 0, stream>>>(
      attnbuf, woT, nullptr, out, nullptr, nullptr, nullptr, M_TOK, H_, H_);
}